// Round 3
// baseline (84.446 us; speedup 1.0000x reference)
//
#include <hip/hip_runtime.h>

#define EPS_F 1e-7f
#define NN 32        // N fixed at 32 by the problem setup
#define MARGIN 3     // conservative range margin (anchor units); fp slop ≤ 0.05
#define NSEG (NN * 6)
#define TPB 512      // 8 waves: 2/SIMD, VGPR budget 256 -> no spill risk
#define CAND_MAX 10240  // worst-case T ≈ 6.9k (band-partition bound) + slack

// rl_fused v3: ONE dispatch, grid (B), 512 threads. Block b owns sample b.
// v2 (~21 µs) was latency-bound on two serialized chains per candidate:
// the 8-deep binary-search LDS chain and the dynamic-trip first-match scan
// reading sh_se from LDS. v3 removes both:
//   - per-candidate segment id precomputed into an LDS byte array (1
//     ds_read_u8 + 1 ds_read_b128 per candidate, pipelined across j)
//   - sorted (s,e) table hoisted to registers; first-match is a fully
//     unrolled 31-step pure-VALU predicated scan (no LDS, no branches)
// Range derivation, exact fp32 predicate, and rcp-GIoU are bit-identical
// to the verified kernel; only accumulation order differs.
__global__ __launch_bounds__(TPB) void rl_fused(
    const float* __restrict__ reg,   // (B, A, 2)
    const float* __restrict__ ann,   // (B, N, 3)
    int c0, int A,
    float* __restrict__ out)         // (B,) final loss per sample
{
    const int b = blockIdx.x;
    const int t = threadIdx.x;
    const int wave = t >> 6;
    const int lane = t & 63;

    __shared__ float2 sh_se[NN];       // sorted (s,e), ascending length
    __shared__ int4   seg[NSEG];       // {l0, r0, lenL|(lenR<<16), start<<16|n<<8|lvl}
    __shared__ int    pfx[NSEG];       // inclusive prefix of candidate counts
    __shared__ unsigned char cand[CAND_MAX];  // flat candidate -> segment id
    __shared__ float  sh_sz[8];
    __shared__ float  red_l[TPB / 64], red_p[TPB / 64];

    // SIZES as double-exprs cast to f32 — JAX weak-scalar promotion.
    if (t < 8) {
        const float szc[8] = {
            0.0f,
            (float)(2.23147392 * (22050.0 / 256.0)),
            (float)(2.62519274 * (22050.0 / 256.0)),
            (float)(3.74199546 * (22050.0 / 256.0)),
            (float)(5.78800454 * (22050.0 / 256.0)),
            (float)(8.02371882 * (22050.0 / 256.0)),
            __builtin_inff(), __builtin_inff()
        };
        sh_sz[t] = szc[t];
    }

    // Shfl-based stable rank sort by length (wave 0, lanes 0..31 only) —
    // identical to the verified kernel.
    if (t < NN) {
        const float* an = ann + (size_t)b * (size_t)NN * 3;
        const float s0 = an[t * 3 + 0];
        const float e0 = an[t * 3 + 1];
        const float len = e0 - s0;
        int rank = 0;
#pragma unroll
        for (int j = 0; j < NN; ++j) {
            const float lj = __shfl(len, j, 64);
            rank += (lj < len) || (lj == len && j < t);
        }
        sh_se[rank] = make_float2(s0, e0);
    }
    __syncthreads();

    // Hoist sorted (s,e) into registers: constant-index unrolled copy ->
    // stays in VGPRs (rule: no runtime indexing). Broadcast LDS reads,
    // independent -> pipelined. Used by the pure-VALU first-match scan.
    float sreg[NN], ereg[NN];
#pragma unroll
    for (int i = 0; i < NN; ++i) {
        const float2 se = sh_se[i];
        sreg[i] = se.x;
        ereg[i] = se.y;
    }

    // Per-(gt,lvl) conservative ranges — verified MARGIN superset logic.
    if (t < NSEG) {
        const int n   = t / 6;
        const int lvl = t - n * 6;
        const float2 se = sh_se[n];
        const float s = se.x, e = se.y;
        const float mid   = 0.5f * (s + e);
        const float halfL = 0.5f * (e - s);
        const float lo = sh_sz[lvl];
        const float hi = sh_sz[lvl + 1];
        const int   cnt = c0 >> lvl;
        const float inv = __int_as_float((127 - lvl) << 23);  // 2^-lvl

        // m(pt) = L/2 + |pt - mid|; band => |pt-mid| in [dlo, dhi).
        const float dlo = fmaxf(lo - halfL, 0.0f);
        const float dhi = hi - halfL;                // +inf at lvl 5 is fine
        const float prl = fmaxf(mid + dlo, s);       // right interval
        const float prh = fminf(mid + dhi, e);
        const float pll = fmaxf(mid - dhi, s);       // left interval
        const float plh = fminf(mid - dlo, e);

        int r0 = (int)floorf(prl * inv - 0.5f) - MARGIN;
        int r1 = (int)floorf(prh * inv - 0.5f) + MARGIN;
        int l0 = (int)floorf(pll * inv - 0.5f) - MARGIN;
        int l1 = (int)floorf(plh * inv - 0.5f) + MARGIN;
        r0 = max(r0, 0); r1 = min(r1, cnt - 1);
        l0 = max(l0, 0); l1 = min(l1, cnt - 1);
        if (r1 >= r0) l1 = min(l1, r0 - 1);          // disjoint union
        const int lenL = max(l1 - l0 + 1, 0);
        const int lenR = max(r1 - r0 + 1, 0);
        seg[t] = make_int4(l0, r0, lenL | (lenR << 16), (n << 8) | lvl);
        pfx[t] = lenL + lenR;
    }
    __syncthreads();

    // Hillis-Steele inclusive scan over pfx[0..NSEG-1].
#pragma unroll
    for (int off = 1; off < NSEG; off <<= 1) {
        int add = 0;
        if (t < NSEG && t >= off) add = pfx[t - off];
        __syncthreads();
        if (t < NSEG) pfx[t] += add;
        __syncthreads();
    }
    const int T = min(pfx[NSEG - 1], CAND_MAX);

    // Fill the flat candidate->segment map; pack start into seg.w.
    if (t < NSEG) {
        const int4 sg = seg[t];
        const int count = (sg.z & 0xffff) + (sg.z >> 16);
        const int start = pfx[t] - count;
        seg[t].w = sg.w | (start << 16);
        const int end = min(start + count, CAND_MAX);
        for (int i = start; i < end; ++i) cand[i] = (unsigned char)t;
    }
    __syncthreads();

    const int twoc0 = 2 * c0;
    float loss_sum = 0.0f, pos_sum = 0.0f;

    for (int j = t; j < T; j += TPB) {
        const int sid = cand[j];                       // 1 LDS byte read
        const int4 sg = seg[sid];                      // 1 ds_read_b128
        const int lenL  = sg.z & 0xffff;
        const int start = sg.w >> 16;
        const int n     = (sg.w >> 8) & 0xff;
        const int lvl   = sg.w & 0xff;
        const int local = j - start;
        const int loc = (local < lenL) ? (sg.x + local) : (sg.y + (local - lenL));
        const float scale = __int_as_float((127 + lvl) << 23);  // 2^lvl
        const float inv   = __int_as_float((127 - lvl) << 23);  // 2^-lvl
        const int aoff = twoc0 - (twoc0 >> lvl);

        // Issue the global load EARLY — always in-bounds (loc in [0,cnt)),
        // overlaps with the VALU first-match scan below.
        const float2 g = ((const float2*)reg)[(size_t)b * A + (aoff + loc)];

        const float pt = ((float)loc + 0.5f) * scale;  // bit-exact anchor
        const float lo = sh_sz[lvl];
        const float hi = sh_sz[lvl + 1];
        const float s = sreg[0], e0_ = ereg[0];        // not used; keep names clear
        (void)s; (void)e0_;

        // Own-gt predicate: sh_se via LDS (runtime n -> must not index regs).
        const float2 se = sh_se[n];
        const float l = pt - se.x;
        const float r = se.y - pt;
        const float m = fmaxf(l, r);
        // EXACT reference predicate (fp32, same op order/compares).
        bool valid = (fminf(l, r) >= 0.0f) & (m >= lo) & (m < hi);

        // First-match: fully unrolled 31-step pure-VALU predicated scan
        // over the register-resident sorted table. No LDS, no branches.
        bool taken = false;
#pragma unroll
        for (int n2 = 0; n2 < NN - 1; ++n2) {
            const float l2 = pt - sreg[n2];
            const float r2 = ereg[n2] - pt;
            const float m2 = fmaxf(l2, r2);
            taken |= (n2 < n) & (fminf(l2, r2) >= 0.0f) & (m2 >= lo) & (m2 < hi);
        }
        valid = valid && !taken;

        // GIoU epilogue (rcp; validated absmax 0 vs 3.9e-2 threshold).
        const float b0 = pt - l * inv;
        const float b1 = pt + r * inv;
        const float inter = fmaxf(fminf(b1, g.y) - fmaxf(b0, g.x), 0.0f);
        const float uni = (b1 - b0) + (g.y - g.x) - inter;
        const float iou = inter * __builtin_amdgcn_rcpf(uni + EPS_F);
        const float enc = fmaxf(b1, g.y) - fminf(b0, g.x);
        float giou = iou - (enc - uni) * __builtin_amdgcn_rcpf(enc + EPS_F);
        giou = fminf(fmaxf(giou, -1.0f), 1.0f);
        loss_sum += valid ? (1.0f - giou) : 0.0f;
        pos_sum  += valid ? 1.0f : 0.0f;
    }

    // Wave reduce, cross-wave via LDS, final division in-block.
    for (int o = 32; o > 0; o >>= 1) {
        loss_sum += __shfl_down(loss_sum, o, 64);
        pos_sum  += __shfl_down(pos_sum,  o, 64);
    }
    if (lane == 0) { red_l[wave] = loss_sum; red_p[wave] = pos_sum; }
    __syncthreads();
    if (t == 0) {
        float Ls = 0.0f, Ps = 0.0f;
#pragma unroll
        for (int w = 0; w < TPB / 64; ++w) { Ls += red_l[w]; Ps += red_p[w]; }
        out[b] = Ls / fmaxf(Ps, 1.0f);
    }
}

extern "C" void kernel_launch(void* const* d_in, const int* in_sizes, int n_in,
                              void* d_out, int out_size, void* d_ws, size_t ws_size,
                              hipStream_t stream) {
    const float* reg = (const float*)d_in[0];
    const float* ann = (const float*)d_in[1];
    // d_in[2] = class_id (unused); anchors d_in[3..8] are analytic, not read.
    const int c0 = in_sizes[3];
    const int A = in_sizes[3] + in_sizes[4] + in_sizes[5] +
                  in_sizes[6] + in_sizes[7] + in_sizes[8];
    const int B = out_size;                  // 4
    (void)d_ws; (void)ws_size;

    rl_fused<<<dim3(B), TPB, 0, stream>>>(reg, ann, c0, A, (float*)d_out);
}

// Round 4
// 76.479 us; speedup vs baseline: 1.1042x; 1.1042x over previous
//
#include <hip/hip_runtime.h>

#define EPS_F 1e-7f
#define NN 32        // N fixed at 32 by the problem setup
#define MARGIN 3     // conservative range margin (anchor units); fp slop ≤ 0.05
#define NSEG (NN * 6)
#define TPB 1024     // 16 waves: 4/SIMD for latency hiding; body small -> <=128 VGPR
#define CAND_MAX 24576  // provable worst-case T ~19k (banded-count bound) + slack

// rl_fused v4: ONE dispatch, grid (B), 1024 threads. Block b owns sample b.
// v2/v3 (~21 µs) were bound by per-candidate cost on 4 CUs: v3's 31-step
// unrolled first-match scan is ~155 VALU/candidate, and the LDS chain
// cand[j]->seg->pt serializes per iteration. v4:
//   - per-segment 32-bit OVERLAP MASK of earlier gts whose [s,e] intersects
//     the segment's anchor span (exact fp compares on identical pt values ->
//     conservative superset). Expected popcount ~0 -> first-match is a ctz
//     loop that almost never executes; exact predicate only on set bits.
//   - TPB 1024 (16 waves, 4/SIMD): 4x latency hiding, half the trip count.
//   - wave-0 shfl prefix scan (2 barriers, not 16); u32-packed cand fill.
// Range derivation, exact fp32 predicate, and rcp-GIoU are bit-identical
// to the verified kernel; only accumulation order differs.
__global__ __launch_bounds__(TPB) void rl_fused(
    const float* __restrict__ reg,   // (B, A, 2)
    const float* __restrict__ ann,   // (B, N, 3)
    int c0, int A,
    float* __restrict__ out)         // (B,) final loss per sample
{
    const int b = blockIdx.x;
    const int t = threadIdx.x;
    const int wave = t >> 6;
    const int lane = t & 63;

    __shared__ float2 sh_se[NN];       // sorted (s,e), ascending length
    __shared__ int4   seg[NSEG];       // {l0, r0, lenL|(lenR<<16), start<<16|n<<8|lvl}
    __shared__ int    pfx[NSEG];       // counts, then inclusive prefix
    __shared__ unsigned segmask[NSEG]; // earlier-gt overlap mask per segment
    __shared__ unsigned cand32[CAND_MAX / 4];  // flat candidate -> segment id (bytes)
    __shared__ float  sh_sz[8];
    __shared__ float  red_l[TPB / 64], red_p[TPB / 64];

    // SIZES as double-exprs cast to f32 — JAX weak-scalar promotion.
    if (t < 8) {
        const float szc[8] = {
            0.0f,
            (float)(2.23147392 * (22050.0 / 256.0)),
            (float)(2.62519274 * (22050.0 / 256.0)),
            (float)(3.74199546 * (22050.0 / 256.0)),
            (float)(5.78800454 * (22050.0 / 256.0)),
            (float)(8.02371882 * (22050.0 / 256.0)),
            __builtin_inff(), __builtin_inff()
        };
        sh_sz[t] = szc[t];
    }

    // Shfl-based stable rank sort by length (wave 0, lanes 0..31 only) —
    // identical to the verified kernel.
    if (t < NN) {
        const float* an = ann + (size_t)b * (size_t)NN * 3;
        const float s0 = an[t * 3 + 0];
        const float e0 = an[t * 3 + 1];
        const float len = e0 - s0;
        int rank = 0;
#pragma unroll
        for (int j = 0; j < NN; ++j) {
            const float lj = __shfl(len, j, 64);
            rank += (lj < len) || (lj == len && j < t);
        }
        sh_se[rank] = make_float2(s0, e0);
    }
    __syncthreads();

    // Per-(gt,lvl) conservative ranges — verified MARGIN superset logic —
    // plus the earlier-gt overlap mask.
    if (t < NSEG) {
        const int n   = t / 6;
        const int lvl = t - n * 6;
        const float2 se = sh_se[n];
        const float s = se.x, e = se.y;
        const float mid   = 0.5f * (s + e);
        const float halfL = 0.5f * (e - s);
        const float lo = sh_sz[lvl];
        const float hi = sh_sz[lvl + 1];
        const int   cnt = c0 >> lvl;
        const float inv   = __int_as_float((127 - lvl) << 23);  // 2^-lvl
        const float scale = __int_as_float((127 + lvl) << 23);  // 2^lvl

        // m(pt) = L/2 + |pt - mid|; band => |pt-mid| in [dlo, dhi).
        const float dlo = fmaxf(lo - halfL, 0.0f);
        const float dhi = hi - halfL;                // +inf at lvl 5 is fine
        const float prl = fmaxf(mid + dlo, s);       // right interval
        const float prh = fminf(mid + dhi, e);
        const float pll = fmaxf(mid - dhi, s);       // left interval
        const float plh = fminf(mid - dlo, e);

        int r0 = (int)floorf(prl * inv - 0.5f) - MARGIN;
        int r1 = (int)floorf(prh * inv - 0.5f) + MARGIN;
        int l0 = (int)floorf(pll * inv - 0.5f) - MARGIN;
        int l1 = (int)floorf(plh * inv - 0.5f) + MARGIN;
        r0 = max(r0, 0); r1 = min(r1, cnt - 1);
        l0 = max(l0, 0); l1 = min(l1, cnt - 1);
        if (r1 >= r0) l1 = min(l1, r0 - 1);          // disjoint union
        const int lenL = max(l1 - l0 + 1, 0);
        const int lenR = max(r1 - r0 + 1, 0);
        seg[t] = make_int4(l0, r0, lenL | (lenR << 16), (n << 8) | lvl);
        pfx[t] = lenL + lenR;

        // Anchor-pt span of this segment (same fp expr as the j-loop's pt,
        // so the span test is an exact superset of the in_gt condition).
        const int firstloc = lenL ? l0 : r0;
        const int lastloc  = lenR ? r1 : l1;
        const float ptmin = ((float)firstloc + 0.5f) * scale;
        const float ptmax = ((float)lastloc  + 0.5f) * scale;
        unsigned msk = 0u;
        for (int n2 = 0; n2 < n; ++n2) {
            const float2 o = sh_se[n2];
            // n2 can steal pt only if o.x <= pt <= o.y for some pt in span.
            if ((o.x <= ptmax) & (o.y >= ptmin)) msk |= (1u << n2);
        }
        segmask[t] = msk;
    }
    __syncthreads();

    // Wave-0 shfl inclusive scan over the 192 counts (3 chunks of 64).
    if (wave == 0) {
        int carry = 0;
#pragma unroll
        for (int k = 0; k < 3; ++k) {
            int v = pfx[k * 64 + lane];
#pragma unroll
            for (int o = 1; o < 64; o <<= 1) {
                const int u = __shfl_up(v, o, 64);
                v += (lane >= o) ? u : 0;
            }
            pfx[k * 64 + lane] = v + carry;
            carry += __shfl(v, 63, 64);   // chunk total, broadcast
        }
    }
    __syncthreads();
    const int T = min(pfx[NSEG - 1], CAND_MAX);   // clamp provably inactive

    // Fill the flat candidate->segment byte map (u32-packed); pack start
    // into seg.w high 16 bits (start < 24576 < 2^16).
    if (t < NSEG) {
        const int4 sg = seg[t];
        const int count = (sg.z & 0xffff) + (sg.z >> 16);
        const int start = pfx[t] - count;
        seg[t].w = sg.w | (start << 16);
        unsigned char* cb = (unsigned char*)cand32;
        int i = start;
        const int end = min(start + count, CAND_MAX);
        const unsigned rep = 0x01010101u * (unsigned)t;
        while (i < end && (i & 3)) cb[i++] = (unsigned char)t;
        for (; i + 4 <= end; i += 4) cand32[i >> 2] = rep;
        for (; i < end; ++i) cb[i] = (unsigned char)t;
    }
    __syncthreads();

    const int twoc0 = 2 * c0;
    const unsigned char* cb = (const unsigned char*)cand32;
    float loss_sum = 0.0f, pos_sum = 0.0f;

    for (int j = t; j < T; j += TPB) {
        const int sid = cb[j];                       // 1 LDS byte read
        const int4 sg = seg[sid];                    // 1 ds_read_b128
        unsigned msk = segmask[sid];                 // independent b32 read
        const int lenL  = sg.z & 0xffff;
        const int start = (int)(((unsigned)sg.w) >> 16);
        const int n     = (sg.w >> 8) & 0xff;
        const int lvl   = sg.w & 0xff;
        const int local = j - start;
        const int loc = (local < lenL) ? (sg.x + local) : (sg.y + (local - lenL));
        const float scale = __int_as_float((127 + lvl) << 23);  // 2^lvl
        const float inv   = __int_as_float((127 - lvl) << 23);  // 2^-lvl
        const int aoff = twoc0 - (twoc0 >> lvl);

        // Issue the global load EARLY — always in-bounds (loc in [0,cnt)),
        // overlaps with the predicate work below.
        const float2 g = ((const float2*)reg)[(size_t)b * A + (aoff + loc)];

        const float pt = ((float)loc + 0.5f) * scale;  // bit-exact anchor
        const float lo = sh_sz[lvl];
        const float hi = sh_sz[lvl + 1];
        const float2 se = sh_se[n];
        const float l = pt - se.x;
        const float r = se.y - pt;
        const float m = fmaxf(l, r);
        // EXACT reference predicate (fp32, same op order/compares).
        bool valid = (fminf(l, r) >= 0.0f) & (m >= lo) & (m < hi);

        // First-match via overlap mask: exact predicate only on the (rare)
        // earlier gts whose [s,e] intersects this segment's anchor span.
        while (valid && msk) {
            const int n2 = __builtin_ctz(msk);
            msk &= msk - 1u;
            const float2 o = sh_se[n2];
            const float l2 = pt - o.x;
            const float r2 = o.y - pt;
            const float m2 = fmaxf(l2, r2);
            if ((fminf(l2, r2) >= 0.0f) & (m2 >= lo) & (m2 < hi)) valid = false;
        }

        // GIoU epilogue (rcp; validated absmax 0 vs 3.9e-2 threshold).
        const float b0 = pt - l * inv;
        const float b1 = pt + r * inv;
        const float inter = fmaxf(fminf(b1, g.y) - fmaxf(b0, g.x), 0.0f);
        const float uni = (b1 - b0) + (g.y - g.x) - inter;
        const float iou = inter * __builtin_amdgcn_rcpf(uni + EPS_F);
        const float enc = fmaxf(b1, g.y) - fminf(b0, g.x);
        float giou = iou - (enc - uni) * __builtin_amdgcn_rcpf(enc + EPS_F);
        giou = fminf(fmaxf(giou, -1.0f), 1.0f);
        loss_sum += valid ? (1.0f - giou) : 0.0f;
        pos_sum  += valid ? 1.0f : 0.0f;
    }

    // Wave reduce, cross-wave via LDS, final division in-block.
    for (int o = 32; o > 0; o >>= 1) {
        loss_sum += __shfl_down(loss_sum, o, 64);
        pos_sum  += __shfl_down(pos_sum,  o, 64);
    }
    if (lane == 0) { red_l[wave] = loss_sum; red_p[wave] = pos_sum; }
    __syncthreads();
    if (t < 16) {
        float Ls = red_l[t];
        float Ps = red_p[t];
#pragma unroll
        for (int o = 8; o > 0; o >>= 1) {
            Ls += __shfl_down(Ls, o, 16);
            Ps += __shfl_down(Ps, o, 16);
        }
        if (t == 0) out[b] = Ls / fmaxf(Ps, 1.0f);
    }
}

extern "C" void kernel_launch(void* const* d_in, const int* in_sizes, int n_in,
                              void* d_out, int out_size, void* d_ws, size_t ws_size,
                              hipStream_t stream) {
    const float* reg = (const float*)d_in[0];
    const float* ann = (const float*)d_in[1];
    // d_in[2] = class_id (unused); anchors d_in[3..8] are analytic, not read.
    const int c0 = in_sizes[3];
    const int A = in_sizes[3] + in_sizes[4] + in_sizes[5] +
                  in_sizes[6] + in_sizes[7] + in_sizes[8];
    const int B = out_size;                  // 4
    (void)d_ws; (void)ws_size;

    rl_fused<<<dim3(B), TPB, 0, stream>>>(reg, ann, c0, A, (float*)d_out);
}